// Round 5
// baseline (4909.874 us; speedup 1.0000x reference)
//
#include <hip/hip_runtime.h>

// DRL4TSP pointer-network decoder, fully fused persistent kernel + stage-0 fold.
// R5 = R4 (16 waves/CU occupancy design) + correctness fixes:
//  - QPB 132 -> 136: sQP row stride 544 B = 34*16 -> every row 16B-aligned.
//    R4's odd-row float4 reads were misaligned (UB; pulled uninitialized pad /
//    stale LDS -> right on fresh LDS, wrong on reuse = observed failure mode).
//  - sQP fully zero-initialized (pads included).
//  - 5th barrier at end of scan body restored (orders select vs next step).
//  - tanh/sigmoid reverted to R3-proven __expf/__fdividef forms.
//
// Key algebra (unchanged): with x[b,s] = (static0, static1, load-demand, demand):
//   static_hidden[b,h,s] = W_s[h,:].(x0,x1) + b_s[h]                 (rank-2)
//   base[b,h,s]          = A[h,:].x[b,s] + biasT[h]                  (rank-4)
//   dec@W_ih^T           = G[g,:].(x0,x1)[ptr] + gbias[g]            (rank-2)

#define H 128
#define S 128
#define NBATCH 2048
#define NB 8               // batch elements per block
#define NT 1024            // threads per block (16 waves)
#define NBLK (NBATCH / NB) // 256 blocks
#define BS (NBATCH * S)

// d_ws layout (float offsets; all 16B-aligned)
#define WS_A  0            // float4 A[128]   : rank-4 attention weights
#define WS_AW 512          // float  AW[128]  : attn_W
#define WS_QB 640          // float  QB[128]  : biasT + b_pr+b_pld+b_pd+b_pq
#define WS_GT 768          // float4 GT[512]  : (g0, g1, gbias, 0) per gate-row

// h-state LDS: octant-swizzled, octant stride 20 floats (80 B, 16B-aligned);
// the 8 K-split octants land on distinct bank quads (20*q mod 32 distinct).
#define SHO 20
#define SHB (8 * SHO)      // 160 floats per bb (640 B, 16B-aligned)
#define SHI(bb, h) ((bb) * SHB + (((h) >> 4) * SHO) + ((h) & 15))
#define QPB 136            // qprime row stride: 544 B = 34*16 -> rows 16B-aligned

#define LOG2E 1.44269504088896f

__device__ __forceinline__ float dot4f(float4 a, float4 b, float c) {
  return fmaf(a.x, b.x, fmaf(a.y, b.y, fmaf(a.z, b.z, fmaf(a.w, b.w, c))));
}
// tanh(x) = 1 - 2/(e^{2x}+1); overflow->inf->1, underflow->0->-1 (both correct)
__device__ __forceinline__ float fast_tanh(float x) {
  float e = __expf(2.f * x);
  return 1.f - __fdividef(2.f, e + 1.f);
}
__device__ __forceinline__ float fast_sig(float x) {
  return __fdividef(1.f, 1.f + __expf(-x));
}

// ---------------- stage 0: fold tables -> d_ws ----------------
__global__ __launch_bounds__(512)
void drl4tsp_fold(const float* __restrict__ W_s, const float* __restrict__ b_s,
                  const float* __restrict__ W_ld, const float* __restrict__ b_ld,
                  const float* __restrict__ W_d, const float* __restrict__ b_d,
                  const float* __restrict__ W_ih, const float* __restrict__ b_ih,
                  const float* __restrict__ b_hh,
                  const float* __restrict__ W_pd, const float* __restrict__ b_pd,
                  const float* __restrict__ W_pld, const float* __restrict__ b_pld,
                  const float* __restrict__ b_pq,
                  const float* __restrict__ W_pr, const float* __restrict__ b_pr,
                  const float* __restrict__ attn_W, const float* __restrict__ mark,
                  float* __restrict__ ws, float* __restrict__ out)
{
  const int tid = threadIdx.x;   // 512 threads, 1 block
  {
    // GT[row] = ((W_ih@W_s)[row,0..1], (W_ih@b_s + b_ih + b_hh)[row], 0)
    const float* wr = W_ih + tid * H;
    float g0 = 0.f, g1 = 0.f, gb = 0.f;
    for (int h = 0; h < H; h += 4) {
      float4 w   = *(const float4*)(wr + h);
      float4 s01 = *(const float4*)(W_s + 2 * h);
      float4 s23 = *(const float4*)(W_s + 2 * h + 4);
      float4 bs  = *(const float4*)(b_s + h);
      g0 = fmaf(w.x, s01.x, fmaf(w.y, s01.z, fmaf(w.z, s23.x, fmaf(w.w, s23.z, g0))));
      g1 = fmaf(w.x, s01.y, fmaf(w.y, s01.w, fmaf(w.z, s23.y, fmaf(w.w, s23.w, g1))));
      gb = fmaf(w.x, bs.x,  fmaf(w.y, bs.y,  fmaf(w.z, bs.z,  fmaf(w.w, bs.w,  gb))));
    }
    ((float4*)(ws + WS_GT))[tid] = make_float4(g0, g1, gb + b_ih[tid] + b_hh[tid], 0.f);
  }
  if (tid < H) {
    // A[h], aW[h], combined bias. The size-1 dyn channel broadcasts over the
    // two columns of W_ld / W_d -> effective weight = column sum.
    const int h = tid;
    float a0 = 0.f, a1 = 0.f, a2 = 0.f, a3 = 0.f, bt = 0.f;
    for (int j = 0; j < H; ++j) {
      float pr  = W_pr[h * H + j];
      float pld = W_pld[h * H + j];
      float pd  = W_pd[h * H + j];
      float2 wsv = *(const float2*)(W_s + 2 * j);
      float2 wld = *(const float2*)(W_ld + 2 * j);
      float2 wd  = *(const float2*)(W_d + 2 * j);
      a0 = fmaf(pr, wsv.x, a0);
      a1 = fmaf(pr, wsv.y, a1);
      a2 = fmaf(pld, wld.x + wld.y, a2);
      a3 = fmaf(pd,  wd.x + wd.y,  a3);
      bt += pr * b_s[j] + pld * b_ld[j] + pd * b_d[j];
    }
    ((float4*)(ws + WS_A))[h] = make_float4(a0, a1, a2, a3);
    ws[WS_AW + h] = attn_W[h];
    ws[WS_QB + h] = bt + b_pr[h] + b_pld[h] + b_pd[h] + b_pq[h];
  }
  if (tid == 0) out[2 * BS] = mark[0];
}

// ---------------- main: 128-step fused decode scan ----------------
__global__ __launch_bounds__(NT, 4)
void drl4tsp_fused(const float* __restrict__ st, const float* __restrict__ dyn,
                   const float* __restrict__ W_hh, const float* __restrict__ W_pq,
                   const float* __restrict__ ws, float* __restrict__ out)
{
  __shared__ float4 sX[NB][S];     // folded per-(b,s) inputs (x0,x1,l-d,d)   16 KB
  __shared__ float  sH[NB * SHB];  // h-state (octant-swizzled)                5 KB
  __shared__ alignas(16) float sQP[NB * QPB]; // qprime = q + biasT          4.25 KB
  __shared__ float4 sGT[4 * H];    // gate fold (g0, g1, gbias, 0)             8 KB
  __shared__ float4 sRed[NB * 2];  // per-(bb, wave-half) argmax partials
  __shared__ float  sSelX0[NB];
  __shared__ float  sSelX1[NB];

  const int tid = threadIdx.x;
  const int b0  = blockIdx.x * NB;
  const int gg = tid >> 3, qq = tid & 7;   // matmul: row-group, 8-way K-split (in-wave octet)
  const int wv = tid >> 6, lane = tid & 63;
  const int bbC  = wv >> 1;                // phase-C: 2 waves per batch elem
  const int col  = ((wv & 1) << 6) + lane; // this lane's s-column

  // staging
  for (int i = tid; i < 4 * H; i += NT) sGT[i] = ((const float4*)(ws + WS_GT))[i];
  {
    int bb = tid >> 7, s = tid & (S - 1);  // NB*S == NT: one element each
    int go = (b0 + bb) * 2 * S;
    float x0 = st[go + s];
    float x1 = st[go + S + s];
    float ld = dyn[go + s];
    float dm = dyn[go + S + s];
    sX[bb][s] = make_float4(x0, x1, ld - dm, dm);
  }
  for (int i = tid; i < NB * SHB; i += NT) sH[i] = 0.f;
  for (int i = tid; i < NB * QPB; i += NT) sQP[i] = 0.f;  // pads included
  if (tid < NB) {
    int go = (b0 + tid) * 2 * S;           // dec0 = static_hidden[:,:,0]
    sSelX0[tid] = st[go + 0];
    sSelX1[tid] = st[go + S + 0];
  }
  const float qb = ws[WS_QB + gg];

  // register-resident weights: 4 gate-rows x 16-K slice + W_pq row slice
  float4 rW[4][4];                 // 64 VGPRs
  #pragma unroll
  for (int g = 0; g < 4; ++g) {
    const float* wr = W_hh + (gg + g * H) * H + 16 * qq;
    #pragma unroll
    for (int k = 0; k < 4; ++k) rW[g][k] = *(const float4*)(wr + 4 * k);
  }
  float4 rQ[4];                    // 16 VGPRs
  {
    const float* wr = W_pq + gg * H + 16 * qq;
    #pragma unroll
    for (int k = 0; k < 4; ++k) rQ[k] = *(const float4*)(wr + 4 * k);
  }
  __syncthreads();

  const float4 xA = sX[bbC][col];
  const int shofs = qq * SHO;
  const float4* At  = (const float4*)(ws + WS_A);   // wave-uniform -> s_load
  const float4* AW4 = (const float4*)(ws + WS_AW);  // wave-uniform -> s_load
  float cC = 0.f;                  // c-state for cell (bb=qq, h=gg)

  #pragma unroll 1
  for (int t = 0; t < S; ++t) {
    // ---- Phase A: gates = h @ W_hh^T (this thread: 4 rows, octant qq of K) ----
    float gG[4];
    #pragma unroll
    for (int hf = 0; hf < 2; ++hf) {
      float a0[4], a1[4], a2[4], a3[4];
      #pragma unroll
      for (int j = 0; j < 4; ++j) { a0[j] = 0.f; a1[j] = 0.f; a2[j] = 0.f; a3[j] = 0.f; }
      #pragma unroll
      for (int i = 0; i < 4; ++i) {
        #pragma unroll
        for (int j = 0; j < 4; ++j) {
          const int bb = hf * 4 + j;
          float4 hv = *(const float4*)&sH[bb * SHB + shofs + 4 * i];
          a0[j] = dot4f(rW[0][i], hv, a0[j]);
          a1[j] = dot4f(rW[1][i], hv, a1[j]);
          a2[j] = dot4f(rW[2][i], hv, a2[j]);
          a3[j] = dot4f(rW[3][i], hv, a3[j]);
        }
      }
      // butterfly over the K-octet; keep the bb this thread owns (bb == qq)
      #pragma unroll
      for (int j = 0; j < 4; ++j) {
        const int bb = hf * 4 + j;
        float v0 = a0[j]; v0 += __shfl_xor(v0, 1); v0 += __shfl_xor(v0, 2); v0 += __shfl_xor(v0, 4);
        float v1 = a1[j]; v1 += __shfl_xor(v1, 1); v1 += __shfl_xor(v1, 2); v1 += __shfl_xor(v1, 4);
        float v2 = a2[j]; v2 += __shfl_xor(v2, 1); v2 += __shfl_xor(v2, 2); v2 += __shfl_xor(v2, 4);
        float v3 = a3[j]; v3 += __shfl_xor(v3, 1); v3 += __shfl_xor(v3, 2); v3 += __shfl_xor(v3, 4);
        if (bb == qq) { gG[0] = v0; gG[1] = v1; gG[2] = v2; gG[3] = v3; }
      }
    }
    __syncthreads();   // (1) all sH reads done before h-state update

    // ---- LSTM activation: this thread owns cell (bb=qq, h=gg) ----
    {
      float4 g0 = sGT[gg];
      float4 g1 = sGT[gg + H];
      float4 g2 = sGT[gg + 2 * H];
      float4 g3 = sGT[gg + 3 * H];
      const float x0p = sSelX0[qq], x1p = sSelX1[qq];
      float gi = gG[0] + fmaf(g0.x, x0p, fmaf(g0.y, x1p, g0.z));
      float gf = gG[1] + fmaf(g1.x, x0p, fmaf(g1.y, x1p, g1.z));
      float gc = gG[2] + fmaf(g2.x, x0p, fmaf(g2.y, x1p, g2.z));
      float go = gG[3] + fmaf(g3.x, x0p, fmaf(g3.y, x1p, g3.z));
      cC = fast_sig(gf) * cC + fast_sig(gi) * fast_tanh(gc);
      sH[SHI(qq, gg)] = fast_sig(go) * fast_tanh(cC);
    }
    __syncthreads();   // (2) sH updated before Phase B reads

    // ---- Phase B: qprime = h_new @ W_pq^T + (b_pq + biasT) ----
    {
      float qa[8];
      #pragma unroll
      for (int bb = 0; bb < 8; ++bb) qa[bb] = 0.f;
      #pragma unroll
      for (int i = 0; i < 4; ++i) {
        #pragma unroll
        for (int bb = 0; bb < 8; ++bb) {
          float4 hv = *(const float4*)&sH[bb * SHB + shofs + 4 * i];
          qa[bb] = dot4f(rQ[i], hv, qa[bb]);
        }
      }
      float qsel = 0.f;
      #pragma unroll
      for (int bb = 0; bb < 8; ++bb) {
        float v = qa[bb]; v += __shfl_xor(v, 1); v += __shfl_xor(v, 2); v += __shfl_xor(v, 4);
        if (bb == qq) qsel = v;
      }
      sQP[qq * QPB + gg] = qsel + qb;
    }
    __syncthreads();   // (3) sQP written before Phase C reads

    // ---- Phase C: attention + masked softmax + argmax + select ----
    // One s-column per lane; A/aW via s_load, qprime via LDS broadcast
    // (row base 16B-aligned: QPB*4 = 544 = 34*16).
    float at = 0.f;
    const float* qpp = &sQP[bbC * QPB];
    #pragma unroll 8
    for (int k = 0; k < 32; ++k) {
      float4 qv = *(const float4*)(qpp + 4 * k);
      float4 aw = AW4[k];
      float4 a;
      a = At[4 * k + 0]; at = fmaf(aw.x, fast_tanh(dot4f(a, xA, qv.x)), at);
      a = At[4 * k + 1]; at = fmaf(aw.y, fast_tanh(dot4f(a, xA, qv.y)), at);
      a = At[4 * k + 2]; at = fmaf(aw.z, fast_tanh(dot4f(a, xA, qv.z)), at);
      a = At[4 * k + 3]; at = fmaf(aw.w, fast_tanh(dot4f(a, xA, qv.w)), at);
    }
    // mask2: +10000 for s>=1
    float av = at + ((col == 0) ? 0.f : 10000.f);
    float v = av; int idx = col;
    #pragma unroll
    for (int m = 1; m < 64; m <<= 1) {       // lexicographic (v, -idx): first-occurrence argmax
      float ov = __shfl_xor(v, m);
      int   oi = __shfl_xor(idx, m);
      if (ov > v || (ov == v && oi < idx)) { v = ov; idx = oi; }
    }
    float es = __expf(av - v);
    #pragma unroll
    for (int m = 1; m < 64; m <<= 1) es += __shfl_xor(es, m);
    if (lane == 0) sRed[(bbC << 1) + (wv & 1)] = make_float4(v, __int_as_float(idx), es, 0.f);
    __syncthreads();   // (4) partials visible

    if (lane == 0 && (wv & 1) == 0) {
      float4 r0 = sRed[(bbC << 1) + 0];      // cols 0..63
      float4 r1 = sRed[(bbC << 1) + 1];      // cols 64..127 (all idx > any r0 idx)
      bool take1 = r1.x > r0.x;              // tie -> lower idx -> r0
      float M = take1 ? r1.x : r0.x;
      int   I = take1 ? __float_as_int(r1.y) : __float_as_int(r0.y);
      float esc = r0.z * __expf(r0.x - M) + r1.z * __expf(r1.x - M);
      const int bg = b0 + bbC;
      out[bg * S + t]      = (float)I;       // tour_idx (B,S)
      out[BS + bg * S + t] = -__logf(esc);   // tour_logp (B,S)
      float4 xv = sX[bbC][I];                // dec_{t+1} = static_hidden[:,:,I]
      sSelX0[bbC] = xv.x;
      sSelX1[bbC] = xv.y;
    }
    __syncthreads();   // (5) select visible before next step's LSTM/use
  }
}

extern "C" void kernel_launch(void* const* d_in, const int* in_sizes, int n_in,
                              void* d_out, int out_size, void* d_ws, size_t ws_size,
                              hipStream_t stream) {
  const float* st     = (const float*)d_in[0];
  const float* dyn    = (const float*)d_in[1];
  const float* mark   = (const float*)d_in[2];
  const float* W_s    = (const float*)d_in[3];
  const float* b_s    = (const float*)d_in[4];
  const float* W_ld   = (const float*)d_in[5];
  const float* b_ld   = (const float*)d_in[6];
  const float* W_d    = (const float*)d_in[7];
  const float* b_d    = (const float*)d_in[8];
  const float* W_ih   = (const float*)d_in[9];
  const float* b_ih   = (const float*)d_in[10];
  const float* W_hh   = (const float*)d_in[11];
  const float* b_hh   = (const float*)d_in[12];
  const float* W_pd   = (const float*)d_in[13];
  const float* b_pd   = (const float*)d_in[14];
  const float* W_pld  = (const float*)d_in[15];
  const float* b_pld  = (const float*)d_in[16];
  const float* W_pq   = (const float*)d_in[17];
  const float* b_pq   = (const float*)d_in[18];
  const float* W_pr   = (const float*)d_in[19];
  const float* b_pr   = (const float*)d_in[20];
  const float* attn_W = (const float*)d_in[21];
  float* out = (float*)d_out;
  float* wsf = (float*)d_ws;

  hipLaunchKernelGGL(drl4tsp_fold, dim3(1), dim3(512), 0, stream,
                     W_s, b_s, W_ld, b_ld, W_d, b_d, W_ih, b_ih, b_hh,
                     W_pd, b_pd, W_pld, b_pld, b_pq, W_pr, b_pr, attn_W, mark,
                     wsf, out);
  hipLaunchKernelGGL(drl4tsp_fused, dim3(NBLK), dim3(NT), 0, stream,
                     st, dyn, W_hh, W_pq, wsf, out);
}

// Round 6
// 4659.163 us; speedup vs baseline: 1.0538x; 1.0538x over previous
//
#include <hip/hip_runtime.h>

// DRL4TSP pointer-network decoder, fully fused persistent kernel + stage-0 fold.
// R6 = R5 + register pinning + one fewer barrier:
//  - amdgpu_waves_per_eu(4,4): R5's launch_bounds(1024,4) only set a MINIMUM
//    (VGPR<=128); the allocator targeted 8 waves/EU = 64 VGPR and spilled the
//    weight slice to scratch (FETCH 5.16 GB, WRITE 231 MB = whole 5.2 ms).
//    Pinning max waves/EU to 4 restores the 128-reg budget -> rW/rQ resident.
//  - sH double-buffered by step parity: LSTM writes sH[p^1] while Phase A read
//    sH[p] -> no WAR hazard -> the Phase-A/LSTM barrier is dropped (5 -> 4).
//
// Key algebra (unchanged): with x[b,s] = (static0, static1, load-demand, demand):
//   static_hidden[b,h,s] = W_s[h,:].(x0,x1) + b_s[h]                 (rank-2)
//   base[b,h,s]          = A[h,:].x[b,s] + biasT[h]                  (rank-4)
//   dec@W_ih^T           = G[g,:].(x0,x1)[ptr] + gbias[g]            (rank-2)

#define H 128
#define S 128
#define NBATCH 2048
#define NB 8               // batch elements per block
#define NT 1024            // threads per block (16 waves)
#define NBLK (NBATCH / NB) // 256 blocks
#define BS (NBATCH * S)

// d_ws layout (float offsets; all 16B-aligned)
#define WS_A  0            // float4 A[128]   : rank-4 attention weights
#define WS_AW 512          // float  AW[128]  : attn_W
#define WS_QB 640          // float  QB[128]  : biasT + b_pr+b_pld+b_pd+b_pq
#define WS_GT 768          // float4 GT[512]  : (g0, g1, gbias, 0) per gate-row

// h-state LDS: octant-swizzled, octant stride 20 floats (80 B, 16B-aligned);
// the 8 K-split octants land on distinct bank quads (20*q mod 32 distinct).
#define SHO 20
#define SHB (8 * SHO)      // 160 floats per bb (640 B, 16B-aligned)
#define SHI(bb, h) ((bb) * SHB + (((h) >> 4) * SHO) + ((h) & 15))
#define QPB 136            // qprime row stride: 544 B = 34*16 -> rows 16B-aligned

#define LOG2E 1.44269504088896f

__device__ __forceinline__ float dot4f(float4 a, float4 b, float c) {
  return fmaf(a.x, b.x, fmaf(a.y, b.y, fmaf(a.z, b.z, fmaf(a.w, b.w, c))));
}
// tanh(x) = 1 - 2/(e^{2x}+1); overflow->inf->1, underflow->0->-1 (both correct)
__device__ __forceinline__ float fast_tanh(float x) {
  float e = __expf(2.f * x);
  return 1.f - __fdividef(2.f, e + 1.f);
}
__device__ __forceinline__ float fast_sig(float x) {
  return __fdividef(1.f, 1.f + __expf(-x));
}

// ---------------- stage 0: fold tables -> d_ws ----------------
__global__ __launch_bounds__(512)
void drl4tsp_fold(const float* __restrict__ W_s, const float* __restrict__ b_s,
                  const float* __restrict__ W_ld, const float* __restrict__ b_ld,
                  const float* __restrict__ W_d, const float* __restrict__ b_d,
                  const float* __restrict__ W_ih, const float* __restrict__ b_ih,
                  const float* __restrict__ b_hh,
                  const float* __restrict__ W_pd, const float* __restrict__ b_pd,
                  const float* __restrict__ W_pld, const float* __restrict__ b_pld,
                  const float* __restrict__ b_pq,
                  const float* __restrict__ W_pr, const float* __restrict__ b_pr,
                  const float* __restrict__ attn_W, const float* __restrict__ mark,
                  float* __restrict__ ws, float* __restrict__ out)
{
  const int tid = threadIdx.x;   // 512 threads, 1 block
  {
    // GT[row] = ((W_ih@W_s)[row,0..1], (W_ih@b_s + b_ih + b_hh)[row], 0)
    const float* wr = W_ih + tid * H;
    float g0 = 0.f, g1 = 0.f, gb = 0.f;
    for (int h = 0; h < H; h += 4) {
      float4 w   = *(const float4*)(wr + h);
      float4 s01 = *(const float4*)(W_s + 2 * h);
      float4 s23 = *(const float4*)(W_s + 2 * h + 4);
      float4 bs  = *(const float4*)(b_s + h);
      g0 = fmaf(w.x, s01.x, fmaf(w.y, s01.z, fmaf(w.z, s23.x, fmaf(w.w, s23.z, g0))));
      g1 = fmaf(w.x, s01.y, fmaf(w.y, s01.w, fmaf(w.z, s23.y, fmaf(w.w, s23.w, g1))));
      gb = fmaf(w.x, bs.x,  fmaf(w.y, bs.y,  fmaf(w.z, bs.z,  fmaf(w.w, bs.w,  gb))));
    }
    ((float4*)(ws + WS_GT))[tid] = make_float4(g0, g1, gb + b_ih[tid] + b_hh[tid], 0.f);
  }
  if (tid < H) {
    // A[h], aW[h], combined bias. The size-1 dyn channel broadcasts over the
    // two columns of W_ld / W_d -> effective weight = column sum.
    const int h = tid;
    float a0 = 0.f, a1 = 0.f, a2 = 0.f, a3 = 0.f, bt = 0.f;
    for (int j = 0; j < H; ++j) {
      float pr  = W_pr[h * H + j];
      float pld = W_pld[h * H + j];
      float pd  = W_pd[h * H + j];
      float2 wsv = *(const float2*)(W_s + 2 * j);
      float2 wld = *(const float2*)(W_ld + 2 * j);
      float2 wd  = *(const float2*)(W_d + 2 * j);
      a0 = fmaf(pr, wsv.x, a0);
      a1 = fmaf(pr, wsv.y, a1);
      a2 = fmaf(pld, wld.x + wld.y, a2);
      a3 = fmaf(pd,  wd.x + wd.y,  a3);
      bt += pr * b_s[j] + pld * b_ld[j] + pd * b_d[j];
    }
    ((float4*)(ws + WS_A))[h] = make_float4(a0, a1, a2, a3);
    ws[WS_AW + h] = attn_W[h];
    ws[WS_QB + h] = bt + b_pr[h] + b_pld[h] + b_pd[h] + b_pq[h];
  }
  if (tid == 0) out[2 * BS] = mark[0];
}

// ---------------- main: 128-step fused decode scan ----------------
__global__ __launch_bounds__(NT) __attribute__((amdgpu_waves_per_eu(4, 4)))
void drl4tsp_fused(const float* __restrict__ st, const float* __restrict__ dyn,
                   const float* __restrict__ W_hh, const float* __restrict__ W_pq,
                   const float* __restrict__ ws, float* __restrict__ out)
{
  __shared__ float4 sX[NB][S];     // folded per-(b,s) inputs (x0,x1,l-d,d)   16 KB
  __shared__ float  sH[2][NB * SHB]; // h-state, double-buffered by t parity  10 KB
  __shared__ alignas(16) float sQP[NB * QPB]; // qprime = q + biasT          4.25 KB
  __shared__ float4 sGT[4 * H];    // gate fold (g0, g1, gbias, 0)             8 KB
  __shared__ float4 sRed[NB * 2];  // per-(bb, wave-half) argmax partials
  __shared__ float  sSelX0[NB];
  __shared__ float  sSelX1[NB];

  const int tid = threadIdx.x;
  const int b0  = blockIdx.x * NB;
  const int gg = tid >> 3, qq = tid & 7;   // matmul: row-group, 8-way K-split (in-wave octet)
  const int wv = tid >> 6, lane = tid & 63;
  const int bbC  = wv >> 1;                // phase-C: 2 waves per batch elem
  const int col  = ((wv & 1) << 6) + lane; // this lane's s-column

  // staging
  for (int i = tid; i < 4 * H; i += NT) sGT[i] = ((const float4*)(ws + WS_GT))[i];
  {
    int bb = tid >> 7, s = tid & (S - 1);  // NB*S == NT: one element each
    int go = (b0 + bb) * 2 * S;
    float x0 = st[go + s];
    float x1 = st[go + S + s];
    float ld = dyn[go + s];
    float dm = dyn[go + S + s];
    sX[bb][s] = make_float4(x0, x1, ld - dm, dm);
  }
  for (int i = tid; i < 2 * NB * SHB; i += NT) sH[0][i] = 0.f;  // both buffers
  for (int i = tid; i < NB * QPB; i += NT) sQP[i] = 0.f;        // pads included
  if (tid < NB) {
    int go = (b0 + tid) * 2 * S;           // dec0 = static_hidden[:,:,0]
    sSelX0[tid] = st[go + 0];
    sSelX1[tid] = st[go + S + 0];
  }
  const float qb = ws[WS_QB + gg];

  // register-resident weights: 4 gate-rows x 16-K slice + W_pq row slice
  float4 rW[4][4];                 // 64 VGPRs
  #pragma unroll
  for (int g = 0; g < 4; ++g) {
    const float* wr = W_hh + (gg + g * H) * H + 16 * qq;
    #pragma unroll
    for (int k = 0; k < 4; ++k) rW[g][k] = *(const float4*)(wr + 4 * k);
  }
  float4 rQ[4];                    // 16 VGPRs
  {
    const float* wr = W_pq + gg * H + 16 * qq;
    #pragma unroll
    for (int k = 0; k < 4; ++k) rQ[k] = *(const float4*)(wr + 4 * k);
  }
  __syncthreads();

  const float4 xA = sX[bbC][col];
  const int shofs = qq * SHO;
  const float4* At  = (const float4*)(ws + WS_A);   // wave-uniform -> s_load
  const float4* AW4 = (const float4*)(ws + WS_AW);  // wave-uniform -> s_load
  float cC = 0.f;                  // c-state for cell (bb=qq, h=gg)

  #pragma unroll 1
  for (int t = 0; t < S; ++t) {
    const int p = t & 1;           // read-old = sH[p], write-new = sH[p^1]
    const float* sHr = sH[p];
    float*       sHw = sH[p ^ 1];

    // ---- Phase A: gates = h @ W_hh^T (this thread: 4 rows, octant qq of K) ----
    float gG[4];
    #pragma unroll
    for (int hf = 0; hf < 2; ++hf) {
      float a0[4], a1[4], a2[4], a3[4];
      #pragma unroll
      for (int j = 0; j < 4; ++j) { a0[j] = 0.f; a1[j] = 0.f; a2[j] = 0.f; a3[j] = 0.f; }
      #pragma unroll
      for (int i = 0; i < 4; ++i) {
        #pragma unroll
        for (int j = 0; j < 4; ++j) {
          const int bb = hf * 4 + j;
          float4 hv = *(const float4*)&sHr[bb * SHB + shofs + 4 * i];
          a0[j] = dot4f(rW[0][i], hv, a0[j]);
          a1[j] = dot4f(rW[1][i], hv, a1[j]);
          a2[j] = dot4f(rW[2][i], hv, a2[j]);
          a3[j] = dot4f(rW[3][i], hv, a3[j]);
        }
      }
      // butterfly over the K-octet; keep the bb this thread owns (bb == qq)
      #pragma unroll
      for (int j = 0; j < 4; ++j) {
        const int bb = hf * 4 + j;
        float v0 = a0[j]; v0 += __shfl_xor(v0, 1); v0 += __shfl_xor(v0, 2); v0 += __shfl_xor(v0, 4);
        float v1 = a1[j]; v1 += __shfl_xor(v1, 1); v1 += __shfl_xor(v1, 2); v1 += __shfl_xor(v1, 4);
        float v2 = a2[j]; v2 += __shfl_xor(v2, 1); v2 += __shfl_xor(v2, 2); v2 += __shfl_xor(v2, 4);
        float v3 = a3[j]; v3 += __shfl_xor(v3, 1); v3 += __shfl_xor(v3, 2); v3 += __shfl_xor(v3, 4);
        if (bb == qq) { gG[0] = v0; gG[1] = v1; gG[2] = v2; gG[3] = v3; }
      }
    }
    // no barrier: LSTM writes go to the OTHER sH buffer (no WAR with sHr reads)

    // ---- LSTM activation: this thread owns cell (bb=qq, h=gg) ----
    {
      float4 g0 = sGT[gg];
      float4 g1 = sGT[gg + H];
      float4 g2 = sGT[gg + 2 * H];
      float4 g3 = sGT[gg + 3 * H];
      const float x0p = sSelX0[qq], x1p = sSelX1[qq];
      float gi = gG[0] + fmaf(g0.x, x0p, fmaf(g0.y, x1p, g0.z));
      float gf = gG[1] + fmaf(g1.x, x0p, fmaf(g1.y, x1p, g1.z));
      float gc = gG[2] + fmaf(g2.x, x0p, fmaf(g2.y, x1p, g2.z));
      float go = gG[3] + fmaf(g3.x, x0p, fmaf(g3.y, x1p, g3.z));
      cC = fast_sig(gf) * cC + fast_sig(gi) * fast_tanh(gc);
      sHw[SHI(qq, gg)] = fast_sig(go) * fast_tanh(cC);
    }
    __syncthreads();   // (a) new h visible before Phase B reads

    // ---- Phase B: qprime = h_new @ W_pq^T + (b_pq + biasT) ----
    {
      float qa[8];
      #pragma unroll
      for (int bb = 0; bb < 8; ++bb) qa[bb] = 0.f;
      #pragma unroll
      for (int i = 0; i < 4; ++i) {
        #pragma unroll
        for (int bb = 0; bb < 8; ++bb) {
          float4 hv = *(const float4*)&sHw[bb * SHB + shofs + 4 * i];
          qa[bb] = dot4f(rQ[i], hv, qa[bb]);
        }
      }
      float qsel = 0.f;
      #pragma unroll
      for (int bb = 0; bb < 8; ++bb) {
        float v = qa[bb]; v += __shfl_xor(v, 1); v += __shfl_xor(v, 2); v += __shfl_xor(v, 4);
        if (bb == qq) qsel = v;
      }
      sQP[qq * QPB + gg] = qsel + qb;
    }
    __syncthreads();   // (b) sQP visible before Phase C reads

    // ---- Phase C: attention + masked softmax + argmax + select ----
    // One s-column per lane; A/aW via s_load, qprime via LDS broadcast
    // (row base 16B-aligned: QPB*4 = 544 = 34*16).
    float at = 0.f;
    const float* qpp = &sQP[bbC * QPB];
    #pragma unroll 8
    for (int k = 0; k < 32; ++k) {
      float4 qv = *(const float4*)(qpp + 4 * k);
      float4 aw = AW4[k];
      float4 a;
      a = At[4 * k + 0]; at = fmaf(aw.x, fast_tanh(dot4f(a, xA, qv.x)), at);
      a = At[4 * k + 1]; at = fmaf(aw.y, fast_tanh(dot4f(a, xA, qv.y)), at);
      a = At[4 * k + 2]; at = fmaf(aw.z, fast_tanh(dot4f(a, xA, qv.z)), at);
      a = At[4 * k + 3]; at = fmaf(aw.w, fast_tanh(dot4f(a, xA, qv.w)), at);
    }
    // mask2: +10000 for s>=1
    float av = at + ((col == 0) ? 0.f : 10000.f);
    float v = av; int idx = col;
    #pragma unroll
    for (int m = 1; m < 64; m <<= 1) {       // lexicographic (v, -idx): first-occurrence argmax
      float ov = __shfl_xor(v, m);
      int   oi = __shfl_xor(idx, m);
      if (ov > v || (ov == v && oi < idx)) { v = ov; idx = oi; }
    }
    float es = __expf(av - v);
    #pragma unroll
    for (int m = 1; m < 64; m <<= 1) es += __shfl_xor(es, m);
    if (lane == 0) sRed[(bbC << 1) + (wv & 1)] = make_float4(v, __int_as_float(idx), es, 0.f);
    __syncthreads();   // (c) partials visible

    if (lane == 0 && (wv & 1) == 0) {
      float4 r0 = sRed[(bbC << 1) + 0];      // cols 0..63
      float4 r1 = sRed[(bbC << 1) + 1];      // cols 64..127 (all idx > any r0 idx)
      bool take1 = r1.x > r0.x;              // tie -> lower idx -> r0
      float M = take1 ? r1.x : r0.x;
      int   I = take1 ? __float_as_int(r1.y) : __float_as_int(r0.y);
      float esc = r0.z * __expf(r0.x - M) + r1.z * __expf(r1.x - M);
      const int bg = b0 + bbC;
      out[bg * S + t]      = (float)I;       // tour_idx (B,S)
      out[BS + bg * S + t] = -__logf(esc);   // tour_logp (B,S)
      float4 xv = sX[bbC][I];                // dec_{t+1} = static_hidden[:,:,I]
      sSelX0[bbC] = xv.x;
      sSelX1[bbC] = xv.y;
    }
    __syncthreads();   // (d) select visible before next step's LSTM/use
  }
}

extern "C" void kernel_launch(void* const* d_in, const int* in_sizes, int n_in,
                              void* d_out, int out_size, void* d_ws, size_t ws_size,
                              hipStream_t stream) {
  const float* st     = (const float*)d_in[0];
  const float* dyn    = (const float*)d_in[1];
  const float* mark   = (const float*)d_in[2];
  const float* W_s    = (const float*)d_in[3];
  const float* b_s    = (const float*)d_in[4];
  const float* W_ld   = (const float*)d_in[5];
  const float* b_ld   = (const float*)d_in[6];
  const float* W_d    = (const float*)d_in[7];
  const float* b_d    = (const float*)d_in[8];
  const float* W_ih   = (const float*)d_in[9];
  const float* b_ih   = (const float*)d_in[10];
  const float* W_hh   = (const float*)d_in[11];
  const float* b_hh   = (const float*)d_in[12];
  const float* W_pd   = (const float*)d_in[13];
  const float* b_pd   = (const float*)d_in[14];
  const float* W_pld  = (const float*)d_in[15];
  const float* b_pld  = (const float*)d_in[16];
  const float* W_pq   = (const float*)d_in[17];
  const float* b_pq   = (const float*)d_in[18];
  const float* W_pr   = (const float*)d_in[19];
  const float* b_pr   = (const float*)d_in[20];
  const float* attn_W = (const float*)d_in[21];
  float* out = (float*)d_out;
  float* wsf = (float*)d_ws;

  hipLaunchKernelGGL(drl4tsp_fold, dim3(1), dim3(512), 0, stream,
                     W_s, b_s, W_ld, b_ld, W_d, b_d, W_ih, b_ih, b_hh,
                     W_pd, b_pd, W_pld, b_pld, b_pq, W_pr, b_pr, attn_W, mark,
                     wsf, out);
  hipLaunchKernelGGL(drl4tsp_fused, dim3(NBLK), dim3(NT), 0, stream,
                     st, dyn, W_hh, W_pq, wsf, out);
}

// Round 7
// 4475.429 us; speedup vs baseline: 1.0971x; 1.0411x over previous
//
#include <hip/hip_runtime.h>

// DRL4TSP pointer-network decoder, fully fused persistent kernel + stage-0 fold.
// R7: back to the proven NT=512 / VGPR-resident-weights regime (R2 = 3.57 ms;
// NT=1024 is structurally infeasible: 16 waves/block forces <=128 regs/thread,
// weights alone are 80 -> compiler remats weight loads into the loop = R5/R6's
// 5.6 GB refetch). New in R7 vs R2:
//  - FUSED PASS: Phase B(t) and Phase A(t+1) both consume h_new(t) -> one LDS
//    pass computes q(t) AND next-step gates W_hh*h (kept in regs across C).
//    Halves h-reads (128->64 ds_read_b128/thr/step), 4->3 barriers, 5 dot
//    chains share addressing, sH single-buffered. First iter: gG=0 (h0=0).
//  - gate-folds in registers (from d_ws), not LDS.
//  - exp2-native tanh/sigmoid (5 instr), validated in R4 call-1.
//  - Phase C as 4 independent accumulation chains (tanh latency cover).
//
// Key algebra (unchanged): with x[b,s] = (static0, static1, load-demand, demand):
//   static_hidden[b,h,s] = W_s[h,:].(x0,x1) + b_s[h]                 (rank-2)
//   base[b,h,s]          = A[h,:].x[b,s] + biasT[h]                  (rank-4)
//   dec@W_ih^T           = G[g,:].(x0,x1)[ptr] + gbias[g]            (rank-2)

#define H 128
#define S 128
#define NBATCH 2048
#define NB 8               // batch elements per block
#define NT 512             // threads per block (8 waves)
#define NBLK (NBATCH / NB) // 256 blocks
#define BS (NBATCH * S)

// d_ws layout (float offsets; all 16B-aligned)
#define WS_A  0            // float4 A[128]   : rank-4 attention weights
#define WS_AW 512          // float  AW[128]  : attn_W
#define WS_QB 640          // float  QB[128]  : biasT + b_pr+b_pld+b_pd+b_pq
#define WS_GT 768          // float4 GT[512]  : (g0, g1, gbias, 0) per gate-row

// h-state LDS layout: quarter-swizzled, stride 36 (16B-aligned, distinct banks
// across the 4 K-split quarters; same-address reads broadcast over lane/4)
#define SHQ 36
#define SHB (4 * SHQ)      // 144 floats per bb
#define SHI(bb, h) ((bb) * SHB + (((h) >> 5) * SHQ) + ((h) & 31))
#define QPB 136            // qprime row stride: 544 B = 34*16 -> rows 16B-aligned

#define LOG2E 1.44269504088896f

__device__ __forceinline__ float dot4f(float4 a, float4 b, float c) {
  return fmaf(a.x, b.x, fmaf(a.y, b.y, fmaf(a.z, b.z, fmaf(a.w, b.w, c))));
}
// tanh(x) = 1 - 2/(exp2(2*log2e*x)+1): overflow->inf->1, underflow->0->-1.
__device__ __forceinline__ float fast_tanh(float x) {
  float e = __builtin_amdgcn_exp2f(x * (2.f * LOG2E));
  return fmaf(-2.f, __builtin_amdgcn_rcpf(e + 1.f), 1.f);
}
__device__ __forceinline__ float fast_sig(float x) {
  float e = __builtin_amdgcn_exp2f(x * -LOG2E);
  return __builtin_amdgcn_rcpf(1.f + e);
}

// ---------------- stage 0: fold tables -> d_ws ----------------
__global__ __launch_bounds__(512)
void drl4tsp_fold(const float* __restrict__ W_s, const float* __restrict__ b_s,
                  const float* __restrict__ W_ld, const float* __restrict__ b_ld,
                  const float* __restrict__ W_d, const float* __restrict__ b_d,
                  const float* __restrict__ W_ih, const float* __restrict__ b_ih,
                  const float* __restrict__ b_hh,
                  const float* __restrict__ W_pd, const float* __restrict__ b_pd,
                  const float* __restrict__ W_pld, const float* __restrict__ b_pld,
                  const float* __restrict__ b_pq,
                  const float* __restrict__ W_pr, const float* __restrict__ b_pr,
                  const float* __restrict__ attn_W, const float* __restrict__ mark,
                  float* __restrict__ ws, float* __restrict__ out)
{
  const int tid = threadIdx.x;   // 512 threads, 1 block
  {
    // GT[row] = ((W_ih@W_s)[row,0..1], (W_ih@b_s + b_ih + b_hh)[row], 0)
    const float* wr = W_ih + tid * H;
    float g0 = 0.f, g1 = 0.f, gb = 0.f;
    for (int h = 0; h < H; h += 4) {
      float4 w   = *(const float4*)(wr + h);
      float4 s01 = *(const float4*)(W_s + 2 * h);
      float4 s23 = *(const float4*)(W_s + 2 * h + 4);
      float4 bs  = *(const float4*)(b_s + h);
      g0 = fmaf(w.x, s01.x, fmaf(w.y, s01.z, fmaf(w.z, s23.x, fmaf(w.w, s23.z, g0))));
      g1 = fmaf(w.x, s01.y, fmaf(w.y, s01.w, fmaf(w.z, s23.y, fmaf(w.w, s23.w, g1))));
      gb = fmaf(w.x, bs.x,  fmaf(w.y, bs.y,  fmaf(w.z, bs.z,  fmaf(w.w, bs.w,  gb))));
    }
    ((float4*)(ws + WS_GT))[tid] = make_float4(g0, g1, gb + b_ih[tid] + b_hh[tid], 0.f);
  }
  if (tid < H) {
    // A[h], aW[h], combined bias. The size-1 dyn channel broadcasts over the
    // two columns of W_ld / W_d -> effective weight = column sum.
    const int h = tid;
    float a0 = 0.f, a1 = 0.f, a2 = 0.f, a3 = 0.f, bt = 0.f;
    for (int j = 0; j < H; ++j) {
      float pr  = W_pr[h * H + j];
      float pld = W_pld[h * H + j];
      float pd  = W_pd[h * H + j];
      float2 wsv = *(const float2*)(W_s + 2 * j);
      float2 wld = *(const float2*)(W_ld + 2 * j);
      float2 wd  = *(const float2*)(W_d + 2 * j);
      a0 = fmaf(pr, wsv.x, a0);
      a1 = fmaf(pr, wsv.y, a1);
      a2 = fmaf(pld, wld.x + wld.y, a2);
      a3 = fmaf(pd,  wd.x + wd.y,  a3);
      bt += pr * b_s[j] + pld * b_ld[j] + pd * b_d[j];
    }
    ((float4*)(ws + WS_A))[h] = make_float4(a0, a1, a2, a3);
    ws[WS_AW + h] = attn_W[h];
    ws[WS_QB + h] = bt + b_pr[h] + b_pld[h] + b_pd[h] + b_pq[h];
  }
  if (tid == 0) out[2 * BS] = mark[0];
}

// ---------------- main: 128-step fused decode scan ----------------
__global__ __launch_bounds__(NT, 2)
void drl4tsp_fused(const float* __restrict__ st, const float* __restrict__ dyn,
                   const float* __restrict__ W_hh, const float* __restrict__ W_pq,
                   const float* __restrict__ ws, float* __restrict__ out)
{
  __shared__ float4 sX[NB][S];     // folded per-(b,s) inputs (x0,x1,l-d,d)   16 KB
  __shared__ float  sH[NB * SHB];  // h-state (quarter-swizzled, single buf) 4.5 KB
  __shared__ alignas(16) float sQP[NB * QPB]; // qprime = q + biasT         4.25 KB
  __shared__ float  sSelX0[NB];
  __shared__ float  sSelX1[NB];

  const int tid = threadIdx.x;
  const int b0  = blockIdx.x * NB;
  const int gg = tid >> 2, qq = tid & 3;       // matmul: 4-way K-split, partners adjacent
  const int wv = tid >> 6, lane = tid & 63;    // attention: wave wv <-> batch bb=wv
  const int bbA = 2 * qq, bbB = 2 * qq + 1;

  // per-thread folds from d_ws (once)
  float gt0v[4], gt1v[4], gtbv[4];
  #pragma unroll
  for (int g = 0; g < 4; ++g) {
    float4 v = ((const float4*)(ws + WS_GT))[gg + g * H];
    gt0v[g] = v.x; gt1v[g] = v.y; gtbv[g] = v.z;
  }
  const float qb = ws[WS_QB + gg];

  // staging
  for (int i = tid; i < NB * S; i += NT) {
    int bb = i >> 7, s = i & (S - 1);
    int go = (b0 + bb) * 2 * S;
    float x0 = st[go + s];
    float x1 = st[go + S + s];
    float ld = dyn[go + s];
    float dm = dyn[go + S + s];
    sX[bb][s] = make_float4(x0, x1, ld - dm, dm);
  }
  for (int i = tid; i < NB * SHB; i += NT) sH[i] = 0.f;
  for (int i = tid; i < NB * QPB; i += NT) sQP[i] = 0.f;
  if (tid < NB) {
    int go = (b0 + tid) * 2 * S;               // dec0 = static_hidden[:,:,0]
    sSelX0[tid] = st[go + 0];
    sSelX1[tid] = st[go + S + 0];
  }

  // register-resident weights: 4 gate-rows x 32-K slice + W_pq row slice
  float4 rW[4][8];                 // 128 regs
  #pragma unroll
  for (int g = 0; g < 4; ++g) {
    const float* wr = W_hh + (gg + g * H) * H + 32 * qq;
    #pragma unroll
    for (int k = 0; k < 8; ++k) rW[g][k] = *(const float4*)(wr + 4 * k);
  }
  float4 rQ[8];                    // 32 regs
  {
    const float* wr = W_pq + gg * H + 32 * qq;
    #pragma unroll
    for (int k = 0; k < 8; ++k) rQ[k] = *(const float4*)(wr + 4 * k);
  }
  __syncthreads();

  const float4 xA = sX[wv][lane];
  const float4 xB = sX[wv][lane + 64];
  const int shofs = qq * SHQ;
  const float4* At  = (const float4*)(ws + WS_A);   // wave-uniform -> s_load
  const float4* AW4 = (const float4*)(ws + WS_AW);  // wave-uniform -> s_load
  float cA = 0.f, cB = 0.f;        // c-state for cells (bbA,gg), (bbB,gg)
  float gGA[4] = {0.f, 0.f, 0.f, 0.f};  // W_hh·h partial gates; h0=0 -> 0
  float gGB[4] = {0.f, 0.f, 0.f, 0.f};

  #pragma unroll 1
  for (int t = 0; t < S; ++t) {
    // ---- LSTM activation (uses gG from prev iter's fused pass; h0 case = 0) ----
    {
      const float x0p = sSelX0[bbA], x1p = sSelX1[bbA];
      float gi = gGA[0] + fmaf(gt0v[0], x0p, fmaf(gt1v[0], x1p, gtbv[0]));
      float gf = gGA[1] + fmaf(gt0v[1], x0p, fmaf(gt1v[1], x1p, gtbv[1]));
      float gc = gGA[2] + fmaf(gt0v[2], x0p, fmaf(gt1v[2], x1p, gtbv[2]));
      float go = gGA[3] + fmaf(gt0v[3], x0p, fmaf(gt1v[3], x1p, gtbv[3]));
      cA = fast_sig(gf) * cA + fast_sig(gi) * fast_tanh(gc);
      sH[SHI(bbA, gg)] = fast_sig(go) * fast_tanh(cA);
    }
    {
      const float x0p = sSelX0[bbB], x1p = sSelX1[bbB];
      float gi = gGB[0] + fmaf(gt0v[0], x0p, fmaf(gt1v[0], x1p, gtbv[0]));
      float gf = gGB[1] + fmaf(gt0v[1], x0p, fmaf(gt1v[1], x1p, gtbv[1]));
      float gc = gGB[2] + fmaf(gt0v[2], x0p, fmaf(gt1v[2], x1p, gtbv[2]));
      float go = gGB[3] + fmaf(gt0v[3], x0p, fmaf(gt1v[3], x1p, gtbv[3]));
      cB = fast_sig(gf) * cB + fast_sig(gi) * fast_tanh(gc);
      sH[SHI(bbB, gg)] = fast_sig(go) * fast_tanh(cB);
    }
    __syncthreads();   // (1) h_new visible

    // ---- FUSED pass over h_new: q(t) = W_pq·h  AND  gates(t+1) = W_hh·h ----
    // 5 dot-chains x 8 bb share the same 64 ds_read_b128.
    #pragma unroll
    for (int hf = 0; hf < 2; ++hf) {
      float a0[4], a1[4], a2[4], a3[4], aq[4];
      #pragma unroll
      for (int j = 0; j < 4; ++j) { a0[j]=0.f; a1[j]=0.f; a2[j]=0.f; a3[j]=0.f; aq[j]=0.f; }
      #pragma unroll
      for (int i = 0; i < 8; ++i) {
        #pragma unroll
        for (int j = 0; j < 4; ++j) {
          const int bb = hf * 4 + j;
          float4 hv = *(const float4*)&sH[bb * SHB + shofs + 4 * i];
          a0[j] = dot4f(rW[0][i], hv, a0[j]);
          a1[j] = dot4f(rW[1][i], hv, a1[j]);
          a2[j] = dot4f(rW[2][i], hv, a2[j]);
          a3[j] = dot4f(rW[3][i], hv, a3[j]);
          aq[j] = dot4f(rQ[i],    hv, aq[j]);
        }
      }
      #pragma unroll
      for (int j = 0; j < 4; ++j) {
        const int bb = hf * 4 + j;
        float v0 = a0[j]; v0 += __shfl_xor(v0, 1); v0 += __shfl_xor(v0, 2);
        float v1 = a1[j]; v1 += __shfl_xor(v1, 1); v1 += __shfl_xor(v1, 2);
        float v2 = a2[j]; v2 += __shfl_xor(v2, 1); v2 += __shfl_xor(v2, 2);
        float v3 = a3[j]; v3 += __shfl_xor(v3, 1); v3 += __shfl_xor(v3, 2);
        float vq = aq[j]; vq += __shfl_xor(vq, 1); vq += __shfl_xor(vq, 2);
        if (bb == bbA) { gGA[0]=v0; gGA[1]=v1; gGA[2]=v2; gGA[3]=v3; sQP[bbA*QPB+gg] = vq + qb; }
        if (bb == bbB) { gGB[0]=v0; gGB[1]=v1; gGB[2]=v2; gGB[3]=v3; sQP[bbB*QPB+gg] = vq + qb; }
      }
    }
    __syncthreads();   // (2) sQP visible

    // ---- Phase C: attention + masked softmax + argmax + select ----
    // 2 columns/lane, 4 independent accumulation chains (tanh latency cover).
    float at0a = 0.f, at0b = 0.f, at1a = 0.f, at1b = 0.f;
    const float* qpp = &sQP[wv * QPB];
    #pragma unroll 4
    for (int k = 0; k < 32; ++k) {
      float4 qv = *(const float4*)(qpp + 4 * k);
      float4 aw = AW4[k];
      float4 a;
      a = At[4 * k + 0];
      at0a = fmaf(aw.x, fast_tanh(dot4f(a, xA, qv.x)), at0a);
      at1a = fmaf(aw.x, fast_tanh(dot4f(a, xB, qv.x)), at1a);
      a = At[4 * k + 1];
      at0b = fmaf(aw.y, fast_tanh(dot4f(a, xA, qv.y)), at0b);
      at1b = fmaf(aw.y, fast_tanh(dot4f(a, xB, qv.y)), at1b);
      a = At[4 * k + 2];
      at0a = fmaf(aw.z, fast_tanh(dot4f(a, xA, qv.z)), at0a);
      at1a = fmaf(aw.z, fast_tanh(dot4f(a, xB, qv.z)), at1a);
      a = At[4 * k + 3];
      at0b = fmaf(aw.w, fast_tanh(dot4f(a, xA, qv.w)), at0b);
      at1b = fmaf(aw.w, fast_tanh(dot4f(a, xB, qv.w)), at1b);
    }
    // mask2: +10000 for s>=1, +0 for s==0
    float a0v = (at0a + at0b) + ((lane == 0) ? 0.f : 10000.f);
    float a1v = (at1a + at1b) + 10000.f;
    float v; int idx;
    if (a1v > a0v) { v = a1v; idx = lane + 64; } else { v = a0v; idx = lane; }
    #pragma unroll
    for (int m = 1; m < 64; m <<= 1) {       // lexicographic (v, -idx): first-occurrence argmax
      float ov = __shfl_xor(v, m);
      int   oi = __shfl_xor(idx, m);
      if (ov > v || (ov == v && oi < idx)) { v = ov; idx = oi; }
    }
    float es = __builtin_amdgcn_exp2f((a0v - v) * LOG2E)
             + __builtin_amdgcn_exp2f((a1v - v) * LOG2E);
    #pragma unroll
    for (int m = 1; m < 64; m <<= 1) es += __shfl_xor(es, m);
    if (lane == 0) {
      const int bg = b0 + wv;
      out[bg * S + t]      = (float)idx;     // tour_idx (B,S)
      out[BS + bg * S + t] = -__logf(es);    // tour_logp (B,S)
      float4 xv = sX[wv][idx];               // dec_{t+1} = static_hidden[:,:,idx]
      sSelX0[wv] = xv.x;
      sSelX1[wv] = xv.y;
    }
    __syncthreads();   // (3) select visible before next step's LSTM
  }
}

extern "C" void kernel_launch(void* const* d_in, const int* in_sizes, int n_in,
                              void* d_out, int out_size, void* d_ws, size_t ws_size,
                              hipStream_t stream) {
  const float* st     = (const float*)d_in[0];
  const float* dyn    = (const float*)d_in[1];
  const float* mark   = (const float*)d_in[2];
  const float* W_s    = (const float*)d_in[3];
  const float* b_s    = (const float*)d_in[4];
  const float* W_ld   = (const float*)d_in[5];
  const float* b_ld   = (const float*)d_in[6];
  const float* W_d    = (const float*)d_in[7];
  const float* b_d    = (const float*)d_in[8];
  const float* W_ih   = (const float*)d_in[9];
  const float* b_ih   = (const float*)d_in[10];
  const float* W_hh   = (const float*)d_in[11];
  const float* b_hh   = (const float*)d_in[12];
  const float* W_pd   = (const float*)d_in[13];
  const float* b_pd   = (const float*)d_in[14];
  const float* W_pld  = (const float*)d_in[15];
  const float* b_pld  = (const float*)d_in[16];
  const float* W_pq   = (const float*)d_in[17];
  const float* b_pq   = (const float*)d_in[18];
  const float* W_pr   = (const float*)d_in[19];
  const float* b_pr   = (const float*)d_in[20];
  const float* attn_W = (const float*)d_in[21];
  float* out = (float*)d_out;
  float* wsf = (float*)d_ws;

  hipLaunchKernelGGL(drl4tsp_fold, dim3(1), dim3(512), 0, stream,
                     W_s, b_s, W_ld, b_ld, W_d, b_d, W_ih, b_ih, b_hh,
                     W_pd, b_pd, W_pld, b_pld, b_pq, W_pr, b_pr, attn_W, mark,
                     wsf, out);
  hipLaunchKernelGGL(drl4tsp_fused, dim3(NBLK), dim3(NT), 0, stream,
                     st, dyn, W_hh, W_pq, wsf, out);
}